// Round 1
// baseline (94105.463 us; speedup 1.0000x reference)
//
#include <hip/hip_runtime.h>

#define H   200
#define H4  800
#define T   100
#define BT  16        // batch elements per workgroup
#define THREADS 512   // 16 b-groups x 32 column-threads

__device__ __forceinline__ float sigmoidf_fast(float v) {
    return 1.0f / (1.0f + __expf(-v));
}
// tanh via 2*sigmoid(2x)-1: safe at both extremes (exp(+inf)->inf -> 0 -> -1; exp(-inf)->0 -> +1)
__device__ __forceinline__ float tanhf_fast(float v) {
    return 2.0f / (1.0f + __expf(-2.0f * v)) - 1.0f;
}

// acc[g][u*4+e] += hsrc[k] * M[k][g*H + 4*qc[u] + e]  over k in [0,H)
__device__ __forceinline__ void accum_mat(const float* __restrict__ M,
                                          const float* __restrict__ hsrc,
                                          const int qc0, const int qc1,
                                          float (&acc)[4][8]) {
    for (int k = 0; k < H; k += 4) {
        const float4 h4 = *(const float4*)(hsrc + k);
#pragma unroll
        for (int kk = 0; kk < 4; ++kk) {
            const float hk = (kk == 0) ? h4.x : (kk == 1) ? h4.y : (kk == 2) ? h4.z : h4.w;
            const float* row = M + (k + kk) * H4;
#pragma unroll
            for (int g = 0; g < 4; ++g) {
#pragma unroll
                for (int u = 0; u < 2; ++u) {
                    const int col = g * H + 4 * (u == 0 ? qc0 : qc1);
                    const float4 w = *(const float4*)(row + col);
                    acc[g][u * 4 + 0] += hk * w.x;
                    acc[g][u * 4 + 1] += hk * w.y;
                    acc[g][u * 4 + 2] += hk * w.z;
                    acc[g][u * 4 + 3] += hk * w.w;
                }
            }
        }
    }
}

__device__ __forceinline__ void init_acc_bias(const float* __restrict__ bias,
                                              const int qc0, const int qc1,
                                              float (&acc)[4][8]) {
#pragma unroll
    for (int g = 0; g < 4; ++g) {
#pragma unroll
        for (int u = 0; u < 2; ++u) {
            const float4 bb = *(const float4*)(bias + g * H + 4 * (u == 0 ? qc0 : qc1));
            acc[g][u * 4 + 0] = bb.x;
            acc[g][u * 4 + 1] = bb.y;
            acc[g][u * 4 + 2] = bb.z;
            acc[g][u * 4 + 3] = bb.w;
        }
    }
}

// gate combine + cell update; writes new h into hrow (LDS)
__device__ __forceinline__ void gates_update(float (&acc)[4][8], float* __restrict__ cl,
                                             float* __restrict__ hrow, const int tj) {
#pragma unroll
    for (int u = 0; u < 2; ++u) {
        const int q = (u == 0) ? tj : (32 + tj);
        if (q < 50) {
#pragma unroll
            for (int e = 0; e < 4; ++e) {
                const int idx = u * 4 + e;
                const float iv = sigmoidf_fast(acc[0][idx]);
                const float fv = sigmoidf_fast(acc[1][idx]);
                const float gv = tanhf_fast(acc[2][idx]);
                const float ov = sigmoidf_fast(acc[3][idx]);
                const float c  = fv * cl[idx] + iv * gv;
                cl[idx] = c;
                hrow[4 * q + e] = ov * tanhf_fast(c);
            }
        }
    }
}

__global__ void __launch_bounds__(THREADS)
lstm3_kernel(const float* __restrict__ x,
             const float* __restrict__ W0, const float* __restrict__ U0, const float* __restrict__ b0,
             const float* __restrict__ W1, const float* __restrict__ U1, const float* __restrict__ b1,
             const float* __restrict__ W2, const float* __restrict__ U2, const float* __restrict__ b2,
             const float* __restrict__ Wfc, const float* __restrict__ bfc,
             float* __restrict__ out) {
    __shared__ float hbuf[3][BT][H];

    const int tid = threadIdx.x;
    const int bl  = tid >> 5;   // 0..15 local batch element
    const int tj  = tid & 31;   // 0..31 column thread
    const int b   = blockIdx.x * BT + bl;

    // each thread owns float4 column-quads q0 (always valid) and q1 (valid iff tj<18)
    const int qc0 = tj;
    const int qc1 = (tj < 18) ? (32 + tj) : 49;  // clamp invalid to a safe in-bounds quad

    float cst[3][8];
#pragma unroll
    for (int l = 0; l < 3; ++l)
#pragma unroll
        for (int i = 0; i < 8; ++i) cst[l][i] = 0.0f;

    // zero h state
    for (int i = tid; i < 3 * BT * H; i += THREADS) ((float*)hbuf)[i] = 0.0f;
    __syncthreads();

    float* h0row = &hbuf[0][bl][0];
    float* h1row = &hbuf[1][bl][0];
    float* h2row = &hbuf[2][bl][0];

    for (int t = 0; t < T; ++t) {
        float acc[4][8];

        // -------- layer 0: z = x_t*W0 + h0@U0 + b0 --------
        const float xt = x[b * T + t];
#pragma unroll
        for (int g = 0; g < 4; ++g) {
#pragma unroll
            for (int u = 0; u < 2; ++u) {
                const int col = g * H + 4 * (u == 0 ? qc0 : qc1);
                const float4 bb = *(const float4*)(b0 + col);
                const float4 ww = *(const float4*)(W0 + col);
                acc[g][u * 4 + 0] = bb.x + xt * ww.x;
                acc[g][u * 4 + 1] = bb.y + xt * ww.y;
                acc[g][u * 4 + 2] = bb.z + xt * ww.z;
                acc[g][u * 4 + 3] = bb.w + xt * ww.w;
            }
        }
        accum_mat(U0, h0row, qc0, qc1, acc);
        __syncthreads();                       // all reads of old h0 done
        gates_update(acc, cst[0], h0row, tj);  // write new h0
        __syncthreads();

        // -------- layer 1: z = h0@W1 + h1@U1 + b1 --------
        init_acc_bias(b1, qc0, qc1, acc);
        accum_mat(W1, h0row, qc0, qc1, acc);
        accum_mat(U1, h1row, qc0, qc1, acc);
        __syncthreads();
        gates_update(acc, cst[1], h1row, tj);
        __syncthreads();

        // -------- layer 2: z = h1@W2 + h2@U2 + b2 --------
        init_acc_bias(b2, qc0, qc1, acc);
        accum_mat(W2, h1row, qc0, qc1, acc);
        accum_mat(U2, h2row, qc0, qc1, acc);
        __syncthreads();
        gates_update(acc, cst[2], h2row, tj);
        __syncthreads();
    }

    // -------- dense head: y = tanh(h2 @ Wfc + bfc), 400 cols --------
    float facc[13];
    int   jc[13];
#pragma unroll
    for (int m = 0; m < 13; ++m) {
        const int j = tj + 32 * m;
        jc[m]   = (j < 400) ? j : 399;
        facc[m] = bfc[jc[m]];
    }
    for (int k = 0; k < H; ++k) {
        const float hk = h2row[k];
        const float* row = Wfc + k * 400;
#pragma unroll
        for (int m = 0; m < 13; ++m) facc[m] += hk * row[jc[m]];
    }
#pragma unroll
    for (int m = 0; m < 13; ++m) {
        const int j = tj + 32 * m;
        if (j < 400) out[(size_t)b * 400 + j] = tanhf_fast(facc[m]);
    }
}

extern "C" void kernel_launch(void* const* d_in, const int* in_sizes, int n_in,
                              void* d_out, int out_size, void* d_ws, size_t ws_size,
                              hipStream_t stream) {
    const float* x   = (const float*)d_in[0];
    const float* W0  = (const float*)d_in[1];
    const float* U0  = (const float*)d_in[2];
    const float* b0  = (const float*)d_in[3];
    const float* W1  = (const float*)d_in[4];
    const float* U1  = (const float*)d_in[5];
    const float* b1  = (const float*)d_in[6];
    const float* W2  = (const float*)d_in[7];
    const float* U2  = (const float*)d_in[8];
    const float* b2  = (const float*)d_in[9];
    const float* Wfc = (const float*)d_in[10];
    const float* bfc = (const float*)d_in[11];
    float* out = (float*)d_out;

    const int B = in_sizes[0] / T;   // 8192
    dim3 grid(B / BT), block(THREADS);
    lstm3_kernel<<<grid, block, 0, stream>>>(x, W0, U0, b0, W1, U1, b1, W2, U2, b2, Wfc, bfc, out);
}

// Round 2
// 12284.450 us; speedup vs baseline: 7.6605x; 7.6605x over previous
//
#include <hip/hip_runtime.h>

#define Hdim 200
#define NP   800
#define Tlen 100
#define BT   32          // batch rows per WG
#define KB   7           // K blocks of 32 (200 -> 224 padded)
#define HS   232         // padded h row stride (ushorts): 2-way LDS bank aliasing = free
#define NT   50          // 800/16 col tiles
#define THREADS 640      // 10 waves x 5 col-tiles each
#define CTPW 5
#define MATSZ (KB*NT*64*8)   // 179200 ushorts per packed matrix

typedef float f32x4 __attribute__((ext_vector_type(4)));
typedef short s16x8 __attribute__((ext_vector_type(8)));

__device__ __forceinline__ ushort f2bf(float f) {
    unsigned u = __float_as_uint(f);
    return (ushort)((u + 0x7fffu + ((u >> 16) & 1u)) >> 16);   // RTNE
}
__device__ __forceinline__ float bf2f(ushort s) {
    return __uint_as_float(((unsigned)s) << 16);
}
__device__ __forceinline__ float tanh_fast(float v) {
    return 2.0f / (1.0f + __expf(-2.0f * v)) - 1.0f;
}

// ---- pack 5 recurrent matrices [200][800] fp32 -> bf16 B-fragment layout ----
// dst element (mi, kb, nt, lane, j): B[k = kb*32 + (lane>>4)*8 + j][n' = nt*16 + (lane&15)]
// with gate-interleaved cols: n' = unit*4 + gate  ->  n_src = gate*200 + unit. k>=200 -> 0.
__global__ void pack_weights(const float* __restrict__ U0, const float* __restrict__ W1,
                             const float* __restrict__ U1, const float* __restrict__ W2,
                             const float* __restrict__ U2, ushort* __restrict__ dst) {
    int idx = blockIdx.x * blockDim.x + threadIdx.x;
    if (idx >= 5 * KB * NT * 64) return;
    int lane = idx & 63; int rest = idx >> 6;
    int nt = rest % NT; rest /= NT;
    int kb = rest % KB; int mi = rest / KB;
    const float* src = (mi == 0) ? U0 : (mi == 1) ? W1 : (mi == 2) ? U1 : (mi == 3) ? W2 : U2;
    int np = nt * 16 + (lane & 15);
    int ncol = (np & 3) * Hdim + (np >> 2);          // gate*200 + unit
    int k0 = kb * 32 + (lane >> 4) * 8;
    ushort v[8];
#pragma unroll
    for (int j = 0; j < 8; ++j) {
        int k = k0 + j;
        v[j] = (k < Hdim) ? f2bf(src[k * NP + ncol]) : (ushort)0;
    }
    uint4 o;
    o.x = (unsigned)v[0] | ((unsigned)v[1] << 16);
    o.y = (unsigned)v[2] | ((unsigned)v[3] << 16);
    o.z = (unsigned)v[4] | ((unsigned)v[5] << 16);
    o.w = (unsigned)v[6] | ((unsigned)v[7] << 16);
    ((uint4*)dst)[idx] = o;
}

// one matrix pass: acc[mt][j] += A(hrow) @ B(bmat) over K=224
__device__ __forceinline__ void gemm_pass(f32x4 (&acc)[2][CTPW],
                                          const ushort* __restrict__ hrow,
                                          const ushort* __restrict__ bmat,
                                          int lane, int ct0) {
    const int l15 = lane & 15, q = lane >> 4;
    const ushort* a0p = hrow + l15 * HS + q * 8;
    const ushort* a1p = hrow + (16 + l15) * HS + q * 8;
    const ushort* bp = bmat + (size_t)(ct0 * 64 + lane) * 8;
    for (int kb = 0; kb < KB; ++kb) {
        s16x8 a0 = *(const s16x8*)(a0p + kb * 32);
        s16x8 a1 = *(const s16x8*)(a1p + kb * 32);
        const ushort* bk = bp + (size_t)kb * (NT * 64 * 8);
#pragma unroll
        for (int j = 0; j < CTPW; ++j) {
            s16x8 bf = *(const s16x8*)(bk + j * 64 * 8);
            acc[0][j] = __builtin_amdgcn_mfma_f32_16x16x32_bf16(a0, bf, acc[0][j], 0, 0, 0);
            acc[1][j] = __builtin_amdgcn_mfma_f32_16x16x32_bf16(a1, bf, acc[1][j], 0, 0, 0);
        }
    }
}

// gate combine via intra-quad shuffles; writes new h (bf16) + c (fp32) to LDS
__device__ __forceinline__ void gate_phase(f32x4 (&acc)[2][CTPW],
                                           float (*csl)[Hdim], ushort (*hbl)[HS],
                                           int lane, int ct0) {
    const int l15 = lane & 15, q = lane >> 4, g2 = lane & 3;
#pragma unroll
    for (int mt = 0; mt < 2; ++mt) {
#pragma unroll
        for (int j = 0; j < CTPW; ++j) {
            const int ug = (ct0 + j) * 4 + (l15 >> 2);
#pragma unroll
            for (int r = 0; r < 4; ++r) {
                float v = acc[mt][j][r];
                // lane's own gate activation: sigmoid, or tanh for gate 2
                float scl = (g2 == 2) ? -2.0f : -1.0f;
                float rr = 1.0f / (1.0f + __expf(v * scl));
                float a = (g2 == 2) ? (2.0f * rr - 1.0f) : rr;
                // gather all 4 gate values within the quad (d[idx] holds gate g2^idx)
                float d1 = __shfl_xor(a, 1);
                float d2 = __shfl_xor(a, 2);
                float d3 = __shfl_xor(d1, 2);
                float iv = (g2 == 0) ? a : (g2 == 1) ? d1 : (g2 == 2) ? d2 : d3;
                float fv = (g2 == 0) ? d1 : (g2 == 1) ? a : (g2 == 2) ? d3 : d2;
                float gv = (g2 == 0) ? d2 : (g2 == 1) ? d3 : (g2 == 2) ? a : d1;
                float ov = (g2 == 0) ? d3 : (g2 == 1) ? d2 : (g2 == 2) ? d1 : a;
                int m = mt * 16 + q * 4 + r;
                float cold = csl[m][ug];
                float cn = fv * cold + iv * gv;
                float hn = ov * tanh_fast(cn);
                if (g2 == 0) {
                    csl[m][ug] = cn;
                    hbl[m][ug] = f2bf(hn);
                }
            }
        }
    }
}

__global__ void __launch_bounds__(THREADS, 3)
lstm3_mfma(const float* __restrict__ x,
           const float* __restrict__ W0, const float* __restrict__ b0,
           const float* __restrict__ b1, const float* __restrict__ b2,
           const float* __restrict__ Wfc, const float* __restrict__ bfc,
           const ushort* __restrict__ packed,
           float* __restrict__ out) {
    __shared__ ushort hb[3][BT][HS];     // h state, bf16, A-operand rows (44.5 KB)
    __shared__ float  cs[3][BT][Hdim];   // c state, fp32 (76.8 KB)
    __shared__ float  xT[Tlen][BT];      // x transposed (12.8 KB)

    const int tid = threadIdx.x;
    const int wave = tid >> 6, lane = tid & 63;
    const int l15 = lane & 15, q = lane >> 4;
    const int ct0 = wave * CTPW;
    const int bbase = blockIdx.x * BT;

    for (int i = tid; i < 3 * BT * HS; i += THREADS) ((ushort*)hb)[i] = 0;
    for (int i = tid; i < 3 * BT * Hdim; i += THREADS) ((float*)cs)[i] = 0.0f;
    for (int i = tid; i < BT * Tlen; i += THREADS) {
        int m = i / Tlen, t = i % Tlen;
        xT[t][m] = x[(size_t)(bbase + m) * Tlen + t];
    }

    // per-lane bias / W0 constants (permuted cols), fp32
    float b0r[CTPW], b1r[CTPW], b2r[CTPW], w0r[CTPW];
#pragma unroll
    for (int j = 0; j < CTPW; ++j) {
        int np = (ct0 + j) * 16 + l15;
        int nc = (np & 3) * Hdim + (np >> 2);
        b0r[j] = b0[nc]; b1r[j] = b1[nc]; b2r[j] = b2[nc]; w0r[j] = W0[nc];
    }
    __syncthreads();

    const ushort* pU0 = packed;
    const ushort* pW1 = packed + (size_t)MATSZ;
    const ushort* pU1 = packed + (size_t)2 * MATSZ;
    const ushort* pW2 = packed + (size_t)3 * MATSZ;
    const ushort* pU2 = packed + (size_t)4 * MATSZ;

    for (int t = 0; t < Tlen; ++t) {
        f32x4 acc[2][CTPW];
        // ---- layer 0: z = b0 + x_t*W0 + h0@U0 ----
        float4 xv0 = *(const float4*)&xT[t][q * 4];
        float4 xv1 = *(const float4*)&xT[t][16 + q * 4];
        float xa0[4] = {xv0.x, xv0.y, xv0.z, xv0.w};
        float xa1[4] = {xv1.x, xv1.y, xv1.z, xv1.w};
#pragma unroll
        for (int j = 0; j < CTPW; ++j)
#pragma unroll
            for (int r = 0; r < 4; ++r) {
                acc[0][j][r] = fmaf(xa0[r], w0r[j], b0r[j]);
                acc[1][j][r] = fmaf(xa1[r], w0r[j], b0r[j]);
            }
        gemm_pass(acc, &hb[0][0][0], pU0, lane, ct0);
        __syncthreads();                          // all reads of old h0 done
        gate_phase(acc, cs[0], hb[0], lane, ct0); // write new h0
        __syncthreads();

        // ---- layer 1: z = b1 + h0new@W1 + h1@U1 ----
#pragma unroll
        for (int j = 0; j < CTPW; ++j)
#pragma unroll
            for (int r = 0; r < 4; ++r) { acc[0][j][r] = b1r[j]; acc[1][j][r] = b1r[j]; }
        gemm_pass(acc, &hb[0][0][0], pW1, lane, ct0);
        gemm_pass(acc, &hb[1][0][0], pU1, lane, ct0);
        __syncthreads();
        gate_phase(acc, cs[1], hb[1], lane, ct0);
        __syncthreads();

        // ---- layer 2: z = b2 + h1new@W2 + h2@U2 ----
#pragma unroll
        for (int j = 0; j < CTPW; ++j)
#pragma unroll
            for (int r = 0; r < 4; ++r) { acc[0][j][r] = b2r[j]; acc[1][j][r] = b2r[j]; }
        gemm_pass(acc, &hb[1][0][0], pW2, lane, ct0);
        gemm_pass(acc, &hb[2][0][0], pU2, lane, ct0);
        __syncthreads();
        gate_phase(acc, cs[2], hb[2], lane, ct0);
        __syncthreads();
    }

    // ---- dense head: y = tanh(h2 @ Wfc + bfc), fp32 Wfc, bf16 h2 ----
    const int m = tid / 20;
    const int j0 = (tid % 20) * 20;
    float facc[20];
#pragma unroll
    for (int jj = 0; jj < 20; ++jj) facc[jj] = bfc[j0 + jj];
    for (int k = 0; k < Hdim; ++k) {
        float hk = bf2f(hb[2][m][k]);
        const float* wr = Wfc + (size_t)k * 400 + j0;
#pragma unroll
        for (int jj = 0; jj < 20; jj += 4) {
            float4 w4 = *(const float4*)(wr + jj);
            facc[jj + 0] = fmaf(hk, w4.x, facc[jj + 0]);
            facc[jj + 1] = fmaf(hk, w4.y, facc[jj + 1]);
            facc[jj + 2] = fmaf(hk, w4.z, facc[jj + 2]);
            facc[jj + 3] = fmaf(hk, w4.w, facc[jj + 3]);
        }
    }
    float* orow = out + (size_t)(bbase + m) * 400 + j0;
#pragma unroll
    for (int jj = 0; jj < 20; jj += 4) {
        float4 o4;
        o4.x = tanh_fast(facc[jj + 0]);
        o4.y = tanh_fast(facc[jj + 1]);
        o4.z = tanh_fast(facc[jj + 2]);
        o4.w = tanh_fast(facc[jj + 3]);
        *(float4*)(orow + jj) = o4;
    }
}

extern "C" void kernel_launch(void* const* d_in, const int* in_sizes, int n_in,
                              void* d_out, int out_size, void* d_ws, size_t ws_size,
                              hipStream_t stream) {
    const float* x   = (const float*)d_in[0];
    const float* W0  = (const float*)d_in[1];
    const float* U0  = (const float*)d_in[2];
    const float* b0  = (const float*)d_in[3];
    const float* W1  = (const float*)d_in[4];
    const float* U1  = (const float*)d_in[5];
    const float* b1  = (const float*)d_in[6];
    const float* W2  = (const float*)d_in[7];
    const float* U2  = (const float*)d_in[8];
    const float* b2  = (const float*)d_in[9];
    const float* Wfc = (const float*)d_in[10];
    const float* bfc = (const float*)d_in[11];
    float* out = (float*)d_out;
    ushort* packed = (ushort*)d_ws;

    const int B = in_sizes[0] / Tlen;   // 8192
    const int pack_threads = 5 * KB * NT * 64;
    pack_weights<<<(pack_threads + 255) / 256, 256, 0, stream>>>(U0, W1, U1, W2, U2, packed);
    lstm3_mfma<<<B / BT, THREADS, 0, stream>>>(x, W0, b0, b1, b2, Wfc, bfc, packed, out);
}